// Round 6
// baseline (560.443 us; speedup 1.0000x reference)
//
#include <hip/hip_runtime.h>
#include <hip/hip_bf16.h>
#include <cstdio>

// LoRALinear: out[M,N] = x[M,K] @ W[N,K]^T + bias, W = base + (16/8)*(lora_B @ lora_A)
// M=8192, N=4096, K=4096 (fp32 in/out; internal bf16 MFMA).
// R10: R9 (reg-pipelined 256x256) = 253us, 1086 TF, MfmaUtil 48.8. Tile = 4744cy vs
// 16x16x32 MFMA floor 2484cy. Switch MFMA shape to 32x32x16 (pipe 2495 vs 2075 TF,
// m119 vs m06): floor 2067cy, half the MFMA instructions, same LDS traffic, same
// frag-read count, same reg budget. R9 skeleton (staging, swizzle, vmcnt/lgkm ledger,
// barriers, setprio) unchanged; only frag addressing + MFMA + epilogue change.
// A/B: lane l -> row l&31, k=(l>>5)*8+j. C/D: col=lane&31, row=(reg&3)+8*(reg>>2)+4*hi.

using bf16   = __bf16;
using bf16x8 = __attribute__((ext_vector_type(8))) __bf16;
using f32x16 = __attribute__((ext_vector_type(16))) float;

#define BM 256
#define BN 256
#define BK 64   // two K-slabs of 32
#define WXBLK 2048

// ---------------- kernel 1: fused prep (x-convert || W-build) ----------------
__global__ __launch_bounds__(256) void prep_fused(
    const float* __restrict__ x, const float* __restrict__ base,
    const float* __restrict__ A, const float* __restrict__ Bm,
    bf16* __restrict__ Xb, bf16* __restrict__ Wb,
    long n8x, int K, int rank, float scale) {
    if (blockIdx.x < WXBLK) {
        const long stride = (long)WXBLK * 256;
        for (long i = (long)blockIdx.x * 256 + threadIdx.x; i < n8x; i += stride) {
            const float4 a = reinterpret_cast<const float4*>(x)[2 * i];
            const float4 b = reinterpret_cast<const float4*>(x)[2 * i + 1];
            bf16x8 o;
            o[0] = (bf16)a.x; o[1] = (bf16)a.y; o[2] = (bf16)a.z; o[3] = (bf16)a.w;
            o[4] = (bf16)b.x; o[5] = (bf16)b.y; o[6] = (bf16)b.z; o[7] = (bf16)b.w;
            reinterpret_cast<bf16x8*>(Xb)[i] = o;
        }
    } else {
        const int o = blockIdx.x - WXBLK;
        float br[8];
        const int rr = rank < 8 ? rank : 8;
        for (int r = 0; r < rr; ++r) br[r] = scale * Bm[(size_t)o * rank + r];

        const float* brow = base + (size_t)o * K;
        bf16*        wrow = Wb + (size_t)o * K;

        for (int c = threadIdx.x * 8; c < K; c += 256 * 8) {
            float4 s0 = *reinterpret_cast<const float4*>(brow + c);
            float4 s1 = *reinterpret_cast<const float4*>(brow + c + 4);
            if (rank == 8) {
#pragma unroll
                for (int r = 0; r < 8; ++r) {
                    const float4 a0 = *reinterpret_cast<const float4*>(A + (size_t)r * K + c);
                    const float4 a1 = *reinterpret_cast<const float4*>(A + (size_t)r * K + c + 4);
                    s0.x += br[r] * a0.x; s0.y += br[r] * a0.y;
                    s0.z += br[r] * a0.z; s0.w += br[r] * a0.w;
                    s1.x += br[r] * a1.x; s1.y += br[r] * a1.y;
                    s1.z += br[r] * a1.z; s1.w += br[r] * a1.w;
                }
            } else {
                for (int r = 0; r < rank; ++r) {
                    const float b = scale * Bm[(size_t)o * rank + r];
                    const float4 a0 = *reinterpret_cast<const float4*>(A + (size_t)r * K + c);
                    const float4 a1 = *reinterpret_cast<const float4*>(A + (size_t)r * K + c + 4);
                    s0.x += b * a0.x; s0.y += b * a0.y; s0.z += b * a0.z; s0.w += b * a0.w;
                    s1.x += b * a1.x; s1.y += b * a1.y; s1.z += b * a1.z; s1.w += b * a1.w;
                }
            }
            bf16x8 ov;
            ov[0] = (bf16)s0.x; ov[1] = (bf16)s0.y; ov[2] = (bf16)s0.z; ov[3] = (bf16)s0.w;
            ov[4] = (bf16)s1.x; ov[5] = (bf16)s1.y; ov[6] = (bf16)s1.z; ov[7] = (bf16)s1.w;
            *reinterpret_cast<bf16x8*>(wrow + c) = ov;
        }
    }
}

// ---------------- kernel 2: 256x256 reg-pipelined bf16 GEMM, 32x32x16 MFMA ----------------
// LDS per matrix: [2 buf][2 kslab][256 rows][32 elems]; slab = 16KiB, staged by
// 2 global_load_lds x 16B per thread (linear dest, source pre-swizzled c^((r>>1)&3)).
// 8 waves 2Mx4N; per-wave C 128x64 = 4x2 grid of 32x32 blocks; acc = 8 x f32x16.
// Frag sets per slab: a[4 mb][2 s] + b[2 nb][2 s] = 12 b128 reads.
//   regA(t): read S1 frags (cur.s1); STAGE (t+1).s1->nxt; lgkm(12); 16 MFMA S0; vmcnt(4); bar
//   regB(t): read S0 frags of t+1 (nxt.s0); STAGE (t+2).s0->cur; lgkm(12); 16 MFMA S1; vmcnt(4); bar
__global__ __launch_bounds__(512, 2) void gemm_rp32(
    const bf16* __restrict__ Xb,    // [M,K] row-major
    const bf16* __restrict__ Wb,    // [N,K] row-major
    const float* __restrict__ bias, // [N]
    float* __restrict__ out,        // [M,N] row-major fp32
    int M, int N, int K)
{
    __shared__ __align__(16) bf16 As[2 * 2 * 256 * 32];  // 64 KiB
    __shared__ __align__(16) bf16 Bs[2 * 2 * 256 * 32];  // 64 KiB

    const int tid  = threadIdx.x;     // 0..511
    const int lane = tid & 63;
    const int wv   = tid >> 6;        // wave 0..7
    const int wm   = wv >> 2;         // 0..1
    const int wn   = wv & 3;          // 0..3

    // ---- XCD-aware bijective block swizzle (T1): nwg=512, 512%8==0 ----
    const int nbx = gridDim.x;
    const int nwg = gridDim.x * gridDim.y;
    const int orig = blockIdx.y * nbx + blockIdx.x;
    const int swz = ((nwg & 7) == 0) ? ((orig & 7) * (nwg >> 3) + (orig >> 3)) : orig;
    const int m0 = (swz / nbx) * BM;
    const int n0 = (swz % nbx) * BN;

    const int r32 = lane & 31;        // row-in-32 for A/B frags; col for C/D
    const int hi  = lane >> 5;        // k-half selector for frags; row +4 for C/D

    // ---- staging: slot(i)=i*512+tid; row=slot>>2; src chunk c = (tid&3)^((row>>1)&3)
    const bf16* srcA[2];
    const bf16* srcB[2];
#pragma unroll
    for (int i = 0; i < 2; ++i) {
        const int slot = i * 512 + tid;
        const int row  = slot >> 2;
        const int c    = (tid & 3) ^ ((row >> 1) & 3);
        srcA[i] = Xb + (size_t)(m0 + row) * K + c * 8;
        srcB[i] = Wb + (size_t)(n0 + row) * K + c * 8;
    }
    const int dst0 = (0 * 512 + wv * 64) * 8;
    const int dst1 = (1 * 512 + wv * 64) * 8;

#define STAGE_A(buf, kh, koff)                                                        \
    do {                                                                              \
        __builtin_amdgcn_global_load_lds(                                             \
            (const __attribute__((address_space(1))) void*)(srcA[0] + (koff) + (kh) * 32), \
            (__attribute__((address_space(3))) void*)(As + (buf) * 16384 + (kh) * 8192 + dst0), \
            16, 0, 0);                                                                \
        __builtin_amdgcn_global_load_lds(                                             \
            (const __attribute__((address_space(1))) void*)(srcA[1] + (koff) + (kh) * 32), \
            (__attribute__((address_space(3))) void*)(As + (buf) * 16384 + (kh) * 8192 + dst1), \
            16, 0, 0);                                                                \
    } while (0)
#define STAGE_B(buf, kh, koff)                                                        \
    do {                                                                              \
        __builtin_amdgcn_global_load_lds(                                             \
            (const __attribute__((address_space(1))) void*)(srcB[0] + (koff) + (kh) * 32), \
            (__attribute__((address_space(3))) void*)(Bs + (buf) * 16384 + (kh) * 8192 + dst0), \
            16, 0, 0);                                                                \
        __builtin_amdgcn_global_load_lds(                                             \
            (const __attribute__((address_space(1))) void*)(srcB[1] + (koff) + (kh) * 32), \
            (__attribute__((address_space(3))) void*)(Bs + (buf) * 16384 + (kh) * 8192 + dst1), \
            16, 0, 0);                                                                \
    } while (0)

    // ---- k-invariant fragment element offsets (within a 256x32 slab) ----
    // A-frag (mb,s): row = wm*128 + mb*32 + r32; chunk = s*2 + hi; swz chunk ^= (row>>1)&3
    // B-frag (nb,s): row = wn*64  + nb*32 + r32; same chunk rule.
    int aoff[4][2], boff[2][2];
#pragma unroll
    for (int mb = 0; mb < 4; ++mb) {
        const int row = wm * 128 + mb * 32 + r32;
#pragma unroll
        for (int s = 0; s < 2; ++s)
            aoff[mb][s] = row * 32 + ((s * 2 + hi) ^ ((row >> 1) & 3)) * 8;
    }
#pragma unroll
    for (int nb = 0; nb < 2; ++nb) {
        const int row = wn * 64 + nb * 32 + r32;
#pragma unroll
        for (int s = 0; s < 2; ++s)
            boff[nb][s] = row * 32 + ((s * 2 + hi) ^ ((row >> 1) & 3)) * 8;
    }

    f32x16 acc[4][2] = {};
    bf16x8 aS0[4][2], bS0[2][2];   // frag set S0 (slab0 of current tile)
    bf16x8 aS1[4][2], bS1[2][2];   // frag set S1 (slab1 of current tile)

    const int NT = K / BK;

    // ---- prologue: stage t0 fully + t1.s0; announce t0; preload S0 frags ----
    STAGE_A(0, 0, 0);
    STAGE_B(0, 0, 0);
    STAGE_A(0, 1, 0);
    STAGE_B(0, 1, 0);
    if (NT > 1) {
        STAGE_A(1, 0, BK);
        STAGE_B(1, 0, BK);
        asm volatile("s_waitcnt vmcnt(4)" ::: "memory");   // t0 landed; t1.s0 in flight
    } else {
        asm volatile("s_waitcnt vmcnt(0)" ::: "memory");
    }
    __builtin_amdgcn_s_barrier();
    {
#pragma unroll
        for (int nb = 0; nb < 2; ++nb)
#pragma unroll
            for (int s = 0; s < 2; ++s)
                bS0[nb][s] = *reinterpret_cast<const bf16x8*>(Bs + boff[nb][s]);
#pragma unroll
        for (int mb = 0; mb < 4; ++mb)
#pragma unroll
            for (int s = 0; s < 2; ++s)
                aS0[mb][s] = *reinterpret_cast<const bf16x8*>(As + aoff[mb][s]);
    }

    for (int t = 0; t < NT; ++t) {
        const int cur   = t & 1;
        const int nxt   = cur ^ 1;
        const int koff1 = (t + 1) * BK;
        const int koff2 = (t + 2) * BK;
        const bool pre1 = (t + 1 < NT);
        const bool pre2 = (t + 2 < NT);

        // ================= region A: MFMA slab0 (S0 in regs); prefetch S1 =================
        {
            const bf16* Ab = As + cur * 16384 + 8192;
            const bf16* Bb = Bs + cur * 16384 + 8192;
#pragma unroll
            for (int nb = 0; nb < 2; ++nb)
#pragma unroll
                for (int s = 0; s < 2; ++s)
                    bS1[nb][s] = *reinterpret_cast<const bf16x8*>(Bb + boff[nb][s]);
#pragma unroll
            for (int mb = 0; mb < 4; ++mb)
#pragma unroll
                for (int s = 0; s < 2; ++s)
                    aS1[mb][s] = *reinterpret_cast<const bf16x8*>(Ab + aoff[mb][s]);
            if (pre1) { STAGE_A(nxt, 1, koff1); STAGE_B(nxt, 1, koff1); }   // (t+1).s1
            __builtin_amdgcn_sched_barrier(0);
            asm volatile("s_waitcnt lgkmcnt(12)" ::: "memory");             // S0 frags landed
            __builtin_amdgcn_sched_barrier(0);
            __builtin_amdgcn_s_setprio(1);
#pragma unroll
            for (int s = 0; s < 2; ++s)
#pragma unroll
                for (int mb = 0; mb < 4; ++mb)
#pragma unroll
                    for (int nb = 0; nb < 2; ++nb)
                        acc[mb][nb] = __builtin_amdgcn_mfma_f32_32x32x16_bf16(
                            aS0[mb][s], bS0[nb][s], acc[mb][nb], 0, 0, 0);
            __builtin_amdgcn_s_setprio(0);
            __builtin_amdgcn_sched_barrier(0);
            if (t < NT - 1) {
                // (t+1).s0 (issued t-1.regB or prologue): 4 newer ((t+1).s1) -> vmcnt(4)
                asm volatile("s_waitcnt vmcnt(4)" ::: "memory");
                __builtin_amdgcn_s_barrier();   // announce (t+1).s0; release cur.s0
            }
        }
        // ================= region B: MFMA slab1 (S1 in regs); prefetch next S0 =================
        {
            const bf16* Ab = As + nxt * 16384;
            const bf16* Bb = Bs + nxt * 16384;
            if (pre1) {
#pragma unroll
                for (int nb = 0; nb < 2; ++nb)
#pragma unroll
                    for (int s = 0; s < 2; ++s)
                        bS0[nb][s] = *reinterpret_cast<const bf16x8*>(Bb + boff[nb][s]);
#pragma unroll
                for (int mb = 0; mb < 4; ++mb)
#pragma unroll
                    for (int s = 0; s < 2; ++s)
                        aS0[mb][s] = *reinterpret_cast<const bf16x8*>(Ab + aoff[mb][s]);
            }
            if (pre2) { STAGE_A(cur, 0, koff2); STAGE_B(cur, 0, koff2); }   // (t+2).s0
            __builtin_amdgcn_sched_barrier(0);
            if (pre1) asm volatile("s_waitcnt lgkmcnt(12)" ::: "memory");   // S1 frags landed
            else      asm volatile("s_waitcnt lgkmcnt(0)"  ::: "memory");
            __builtin_amdgcn_sched_barrier(0);
            __builtin_amdgcn_s_setprio(1);
#pragma unroll
            for (int s = 0; s < 2; ++s)
#pragma unroll
                for (int mb = 0; mb < 4; ++mb)
#pragma unroll
                    for (int nb = 0; nb < 2; ++nb)
                        acc[mb][nb] = __builtin_amdgcn_mfma_f32_32x32x16_bf16(
                            aS1[mb][s], bS1[nb][s], acc[mb][nb], 0, 0, 0);
            __builtin_amdgcn_s_setprio(0);
            __builtin_amdgcn_sched_barrier(0);
            if (t < NT - 1) {
                // (t+1).s1 (issued t.regA): newer = (t+2).s0 if staged -> vmcnt(4) else 0
                if (t == NT - 2) asm volatile("s_waitcnt vmcnt(0)" ::: "memory");
                else             asm volatile("s_waitcnt vmcnt(4)" ::: "memory");
                __builtin_amdgcn_s_barrier();   // announce (t+1).s1; release cur.s1
            }
        }
    }

    // ---- epilogue: 32x32 C/D layout col=lane&31, row=(reg&3)+8*(reg>>2)+4*hi ----
#pragma unroll
    for (int mb = 0; mb < 4; ++mb) {
        const int grb = m0 + wm * 128 + mb * 32;
#pragma unroll
        for (int nb = 0; nb < 2; ++nb) {
            const int gc = n0 + wn * 64 + nb * 32 + r32;
            const float bv = bias[gc];
#pragma unroll
            for (int reg = 0; reg < 16; ++reg) {
                const int gr = grb + (reg & 3) + 8 * (reg >> 2) + 4 * hi;
                out[(size_t)gr * N + gc] = acc[mb][nb][reg] + bv;
            }
        }
    }
#undef STAGE_A
#undef STAGE_B
}

extern "C" void kernel_launch(void* const* d_in, const int* in_sizes, int n_in,
                              void* d_out, int out_size, void* d_ws, size_t ws_size,
                              hipStream_t stream) {
    const float* x    = (const float*)d_in[0];
    const float* base = (const float*)d_in[1];
    const float* lA   = (const float*)d_in[2];
    const float* lB   = (const float*)d_in[3];
    const float* bias = (const float*)d_in[4];
    float* out = (float*)d_out;

    const int  N    = in_sizes[4];             // d_out = 4096
    const int  rank = in_sizes[3] / N;         // 8
    const int  K    = in_sizes[2] / rank;      // d_in = 4096
    const long M    = (long)in_sizes[0] / K;   // 8192
    const float scale = 16.0f / (float)rank;   // alpha/rank = 2.0

    bf16* Xb = (bf16*)d_ws;
    bf16* Wb = Xb + (size_t)M * K;
    const size_t need = ((size_t)M * K + (size_t)N * K) * sizeof(bf16);
    if (ws_size < need) {
        fprintf(stderr, "kernel_launch: ws_size %zu < needed %zu\n", ws_size, need);
        return;
    }

    const long n8x = (long)M * K / 8;
    prep_fused<<<dim3((unsigned)(WXBLK + N)), dim3(256), 0, stream>>>(
        x, base, lA, lB, Xb, Wb, n8x, K, rank, scale);

    gemm_rp32<<<dim3(N / BN, (unsigned)(M / BM)), dim3(512), 0, stream>>>(
        Xb, Wb, bias, out, (int)M, N, K);
}